// Round 8
// baseline (123.601 us; speedup 1.0000x reference)
//
#include <hip/hip_runtime.h>
#include <math.h>

#define TT 64
#define NN 64
#define TS 64
#define CC 512
#define NTS (NN * TS)            // 4096
#define NEG (-1e30f)

// output offsets (floats)
#define OUT0 0                    // emissions (64,64,64)
#define OUT1 262144               // gamma     (64,64,64)
#define OUT2 524288               // controls  (63,64,64,2)
#define OUT3 1040384              // read      (63,64,64)
#define OUT4 1298432              // write     (63,64,64)

typedef float f32x4 __attribute__((ext_vector_type(4)));

__device__ __forceinline__ float lse2(float a, float b) {
    float m = fmaxf(a, b);
    float d = fminf(a, b) - m;          // <= 0 (finite args only: inputs clamped >= NEG)
    return m + __logf(1.f + __expf(d));
}

// ---- DPP helpers: classic GCN wave64 inclusive scans ----
template<int ctrl, int rmask>
__device__ __forceinline__ float dppf(float x, float id) {
    return __int_as_float(__builtin_amdgcn_update_dpp(
        __float_as_int(id), __float_as_int(x), ctrl, rmask, 0xF, false));
}
// row_shr:N = 0x110|N ; row_bcast15 = 0x142 (rows 1,3) ; row_bcast31 = 0x143 (rows 2,3)
__device__ __forceinline__ float scan_max64(float v) {
    v = fmaxf(v, dppf<0x111, 0xF>(v, NEG));
    v = fmaxf(v, dppf<0x112, 0xF>(v, NEG));
    v = fmaxf(v, dppf<0x114, 0xF>(v, NEG));
    v = fmaxf(v, dppf<0x118, 0xF>(v, NEG));
    v = fmaxf(v, dppf<0x142, 0xA>(v, NEG));
    v = fmaxf(v, dppf<0x143, 0xC>(v, NEG));
    return v;
}
__device__ __forceinline__ float scan_sum64(float v) {
    v += dppf<0x111, 0xF>(v, 0.f);
    v += dppf<0x112, 0xF>(v, 0.f);
    v += dppf<0x114, 0xF>(v, 0.f);
    v += dppf<0x118, 0xF>(v, 0.f);
    v += dppf<0x142, 0xA>(v, 0.f);
    v += dppf<0x143, 0xC>(v, 0.f);
    return v;
}
// inclusive prefix-LSE over 64 lanes; clamped to NEG so underflowed prefixes
// saturate at -1e30 instead of producing -inf (lse2(-inf,-inf) = NaN).
__device__ __forceinline__ float scan_lse64(float v) {
    float M = __int_as_float(__builtin_amdgcn_readlane(__float_as_int(scan_max64(v)), 63));
    float p = __expf(v - M);
    float S = scan_sum64(p);
    return fmaxf(__logf(S) + M, NEG);
}

// ---------------- Kernel A: gate GEMV (rows t<63), software-pipelined ----------------
// (byte-identical to rounds 6/7 — BW-bound reference point)
__global__ __launch_bounds__(256) void gate_kernel(
    const float* __restrict__ x, const float* __restrict__ w,
    const float* __restrict__ bptr, float* __restrict__ g_ws)
{
    const int lane = threadIdx.x & 63;
    const int wave = (blockIdx.x * blockDim.x + threadIdx.x) >> 6;
    const int nwav = (gridDim.x * blockDim.x) >> 6;
    const float bias = bptr[0];
    const f32x4 wa = ((const f32x4*)w)[lane];
    const f32x4 wb = ((const f32x4*)w)[lane + 64];
    const int R = (TT - 1) * NTS;       // 258048
    const int stride = 2 * nwav;

    int r = 2 * wave;
    f32x4 A0, B0, A1, B1;
    {
        const f32x4* p0 = (const f32x4*)(x + (size_t)r * CC);
        A0 = __builtin_nontemporal_load(&p0[lane]);
        B0 = __builtin_nontemporal_load(&p0[lane + 64]);
        A1 = __builtin_nontemporal_load(&p0[lane + 128]);
        B1 = __builtin_nontemporal_load(&p0[lane + 192]);
    }
    while (true) {
        int rn = r + stride;
        bool more = rn < R;
        f32x4 C0, D0, C1, D1;
        if (more) {
            const f32x4* p1 = (const f32x4*)(x + (size_t)rn * CC);
            C0 = __builtin_nontemporal_load(&p1[lane]);
            D0 = __builtin_nontemporal_load(&p1[lane + 64]);
            C1 = __builtin_nontemporal_load(&p1[lane + 128]);
            D1 = __builtin_nontemporal_load(&p1[lane + 192]);
        }
        float s0 = A0.x*wa.x + A0.y*wa.y + A0.z*wa.z + A0.w*wa.w
                 + B0.x*wb.x + B0.y*wb.y + B0.z*wb.z + B0.w*wb.w;
        float s1 = A1.x*wa.x + A1.y*wa.y + A1.z*wa.z + A1.w*wa.w
                 + B1.x*wb.x + B1.y*wb.y + B1.z*wb.z + B1.w*wb.w;
        #pragma unroll
        for (int off = 32; off; off >>= 1) {
            s0 += __shfl_xor(s0, off);
            s1 += __shfl_xor(s1, off);
        }
        if (lane == 0) {
            float2 gv; gv.x = s0 + bias; gv.y = s1 + bias;
            *(float2*)(g_ws + r) = gv;
        }
        if (!more) break;
        A0 = C0; B0 = D0; A1 = C1; B1 = D1;
        r = rn;
    }
}

// ---------------- Kernel B: fused prep + forward/backward + epilogue ----------------
// One block per n. LDS holds cs/P/alpha/beta for all 64 t.
// Phase 2 register-prefetches cs/P (LDS) and em (global) one t ahead so the
// ds_read latency overlaps the DPP scan chain instead of serializing with it.
__global__ __launch_bounds__(256) void fused_kernel(
    const float* __restrict__ em, const float* __restrict__ g_ws,
    float* __restrict__ out)
{
    __shared__ float cs_s[TT - 1][TS];   // 15.75 KB
    __shared__ float P_s [TT - 1][TS];   // 15.75 KB
    __shared__ float al_s[TT][TS];       // 16 KB
    __shared__ float be_s[TT][TS];       // 16 KB
    __shared__ float pr_s;               // total 63.5 KB < 64 KB

    const int n    = blockIdx.x;
    const int lane = threadIdx.x & 63;
    const int wv   = threadIdx.x >> 6;   // 0..3

    // ---- Phase 1: per-row prep (16 rows per wave) ----
    for (int i = 0; i < 16; ++i) {
        const int t = wv * 16 + i;
        const size_t base = (size_t)t * NTS + (size_t)n * TS;
        float e = em[base + lane];
        out[OUT0 + base + lane] = e;                        // emissions passthrough
        if (t < TT - 1) {
            float g  = g_ws[base + lane];
            float ls = (g >= 0.f) ? -log1pf(__expf(-g)) : (g - log1pf(__expf(g)));
            float c1v = ls - g;
            float2 ctl; ctl.x = ls; ctl.y = c1v;
            ((float2*)(out + OUT2))[base + lane] = ctl;     // controls[t,n,s,:]
            float c1m = (lane == TS - 1) ? 0.f : c1v;
            float cs = scan_sum64(ls) - ls;                 // exclusive prefix sum
            cs_s[t][lane] = cs;
            P_s [t][lane] = c1m + cs;
        }
    }
    __syncthreads();

    // ---- Phase 2: recursions (wave 0 forward, wave 1 backward) ----
    if (wv == 0) {
        float a = (lane == 0) ? em[(size_t)n * TS] : NEG;
        al_s[0][lane] = a;
        float cs = cs_s[0][lane];
        float P  = P_s [0][lane];
        float e1 = em[(size_t)NTS + (size_t)n * TS + lane]; // em[1]
        for (int t = 0; t < TT - 1; ++t) {
            float csn = cs, Pn = P, e1n = e1;
            if (t < TT - 2) {                                // prefetch t+1 operands
                csn = cs_s[t + 1][lane];
                Pn  = P_s [t + 1][lane];
                e1n = em[(size_t)(t + 2) * NTS + (size_t)n * TS + lane];
            }
            a = P + scan_lse64(a - cs) + e1;
            al_s[t + 1][lane] = a;
            cs = csn; P = Pn; e1 = e1n;
        }
        float p = a;
        #pragma unroll
        for (int off = 32; off; off >>= 1) p = lse2(p, __shfl_xor(p, off));
        if (lane == 0) pr_s = p;
    } else if (wv == 1) {
        const int rl = 63 - lane;                            // lane-reversed state
        float b = 0.f;
        be_s[TT - 1][rl] = 0.f;
        float cs = cs_s[TT - 2][rl];
        float P  = P_s [TT - 2][rl];
        float e1 = em[(size_t)(TT - 1) * NTS + (size_t)n * TS + rl];
        for (int t = TT - 2; t >= 0; --t) {
            float csn = cs, Pn = P, e1n = e1;
            if (t > 0) {                                     // prefetch t-1 operands
                csn = cs_s[t - 1][rl];
                Pn  = P_s [t - 1][rl];
                e1n = em[(size_t)t * NTS + (size_t)n * TS + rl];
            }
            b = scan_lse64(P + b + e1) - cs;                 // prefix over lanes = suffix over states
            be_s[t][rl] = b;
            cs = csn; P = Pn; e1 = e1n;
        }
    }
    __syncthreads();

    // ---- Phase 3: gamma / write / read (16 rows per wave) ----
    const float pr = pr_s;
    for (int i = 0; i < 16; ++i) {
        const int t = wv * 16 + i;
        const size_t base = (size_t)t * NTS + (size_t)n * TS;
        float a  = al_s[t][lane];
        float bt = be_s[t][lane];
        float gm = __expf(a + bt - pr);
        out[OUT1 + base + lane] = gm;
        if (t >= 1) out[OUT4 + base - NTS + lane] = gm;      // write[t-1] = gamma[t]
        if (t < TT - 1) {
            float cs = cs_s[t][lane];
            float P  = P_s [t][lane];
            float bn = be_s[t + 1][lane];
            float e1 = em[base + NTS + lane];
            float pu = a - cs;
            float pv = bn + e1 + P - pr;
            float LU = scan_lse64(pu);                       // prefix LSE (i <= k)
            float rv  = __shfl(pv, 63 - lane);               // suffix LSE via reversal
            float LVr = scan_lse64(rv);
            float LV  = __shfl(LVr, 63 - lane);
            float LVe = __shfl_down(LV, 1);                  // exclusive (j > k)
            if (lane == 63) LVe = NEG;
            out[OUT3 + base + lane] = __expf(LU + LVe);
        }
    }
}

extern "C" void kernel_launch(void* const* d_in, const int* in_sizes, int n_in,
                              void* d_out, int out_size, void* d_ws, size_t ws_size,
                              hipStream_t stream) {
    const float* x  = (const float*)d_in[0];
    const float* em = (const float*)d_in[1];
    const float* w  = (const float*)d_in[2];
    const float* bb = (const float*)d_in[3];
    float* out = (float*)d_out;

    float* g_ws = (float*)d_ws;                              // 1 MB

    gate_kernel <<<2048, 256, 0, stream>>>(x, w, bb, g_ws);
    fused_kernel<<<NN,   256, 0, stream>>>(em, g_ws, out);
}

// Round 9
// 115.430 us; speedup vs baseline: 1.0708x; 1.0708x over previous
//
#include <hip/hip_runtime.h>
#include <math.h>

#define TT 64
#define NN 64
#define TS 64
#define CC 512
#define NTS (NN * TS)            // 4096
#define NEG (-1e30f)

// output offsets (floats)
#define OUT0 0                    // emissions (64,64,64)
#define OUT1 262144               // gamma     (64,64,64)
#define OUT2 524288               // controls  (63,64,64,2)
#define OUT3 1040384              // read      (63,64,64)
#define OUT4 1298432              // write     (63,64,64)

typedef float f32x4 __attribute__((ext_vector_type(4)));

__device__ __forceinline__ float lse2(float a, float b) {
    float m = fmaxf(a, b);
    float d = fminf(a, b) - m;          // <= 0 (finite args only: inputs clamped >= NEG)
    return m + __logf(1.f + __expf(d));
}

// ---- DPP helpers: classic GCN wave64 scans/reductions ----
template<int ctrl, int rmask>
__device__ __forceinline__ float dppf(float x, float id) {
    return __int_as_float(__builtin_amdgcn_update_dpp(
        __float_as_int(id), __float_as_int(x), ctrl, rmask, 0xF, false));
}
// row_shr:N = 0x110|N ; row_ror:N = 0x120|N ; quad_perm = 0x00..0xFF
// row_bcast15 = 0x142 (rows 1,3) ; row_bcast31 = 0x143 (rows 2,3)
__device__ __forceinline__ float scan_max64(float v) {
    v = fmaxf(v, dppf<0x111, 0xF>(v, NEG));
    v = fmaxf(v, dppf<0x112, 0xF>(v, NEG));
    v = fmaxf(v, dppf<0x114, 0xF>(v, NEG));
    v = fmaxf(v, dppf<0x118, 0xF>(v, NEG));
    v = fmaxf(v, dppf<0x142, 0xA>(v, NEG));
    v = fmaxf(v, dppf<0x143, 0xC>(v, NEG));
    return v;
}
__device__ __forceinline__ float scan_sum64(float v) {
    v += dppf<0x111, 0xF>(v, 0.f);
    v += dppf<0x112, 0xF>(v, 0.f);
    v += dppf<0x114, 0xF>(v, 0.f);
    v += dppf<0x118, 0xF>(v, 0.f);
    v += dppf<0x142, 0xA>(v, 0.f);
    v += dppf<0x143, 0xC>(v, 0.f);
    return v;
}
// full-wave sum reduction, pure DPP (no LDS pipe); total lands on lane 63.
// quad_perm xor1 (0xB1), xor2 (0x4E); row_ror:4/8 complete each row of 16;
// row_bcast15/31 fold rows. Sum is commutative so rotations suffice.
__device__ __forceinline__ float reduce_sum64_dpp(float v) {
    v += dppf<0xB1,  0xF>(v, 0.f);       // + xor1 neighbor (quad_perm 1,0,3,2)
    v += dppf<0x4E,  0xF>(v, 0.f);       // + xor2 neighbor (quad_perm 2,3,0,1)
    v += dppf<0x124, 0xF>(v, 0.f);       // row_ror:4  -> 2-quad sums
    v += dppf<0x128, 0xF>(v, 0.f);       // row_ror:8  -> full row-of-16 sums
    v += dppf<0x142, 0xA>(v, 0.f);       // row_bcast15: rows 1,3 += rows 0,2
    v += dppf<0x143, 0xC>(v, 0.f);       // row_bcast31: rows 2,3 += lane31 -> lane63 total
    return v;
}
// inclusive prefix-LSE over 64 lanes; clamped to NEG so underflowed prefixes
// saturate at -1e30 instead of producing -inf (lse2(-inf,-inf) = NaN).
__device__ __forceinline__ float scan_lse64(float v) {
    float M = __int_as_float(__builtin_amdgcn_readlane(__float_as_int(scan_max64(v)), 63));
    float p = __expf(v - M);
    float S = scan_sum64(p);
    return fmaxf(__logf(S) + M, NEG);
}

// ---------------- Kernel A: gate GEMV (rows t<63) — pure-DPP reduce ----------------
__global__ __launch_bounds__(256) void gate_kernel(
    const float* __restrict__ x, const float* __restrict__ w,
    const float* __restrict__ bptr, float* __restrict__ g_ws)
{
    const int lane = threadIdx.x & 63;
    const int wave = (blockIdx.x * blockDim.x + threadIdx.x) >> 6;
    const int nwav = (gridDim.x * blockDim.x) >> 6;
    const float bias = bptr[0];
    const f32x4 wa = ((const f32x4*)w)[lane];
    const f32x4 wb = ((const f32x4*)w)[lane + 64];
    const int R = (TT - 1) * NTS;       // 258048
    const int stride = 2 * nwav;

    int r = 2 * wave;
    f32x4 A0, B0, A1, B1;
    {
        const f32x4* p0 = (const f32x4*)(x + (size_t)r * CC);
        A0 = __builtin_nontemporal_load(&p0[lane]);
        B0 = __builtin_nontemporal_load(&p0[lane + 64]);
        A1 = __builtin_nontemporal_load(&p0[lane + 128]);
        B1 = __builtin_nontemporal_load(&p0[lane + 192]);
    }
    while (true) {
        int rn = r + stride;
        bool more = rn < R;
        f32x4 C0, D0, C1, D1;
        if (more) {
            const f32x4* p1 = (const f32x4*)(x + (size_t)rn * CC);
            C0 = __builtin_nontemporal_load(&p1[lane]);
            D0 = __builtin_nontemporal_load(&p1[lane + 64]);
            C1 = __builtin_nontemporal_load(&p1[lane + 128]);
            D1 = __builtin_nontemporal_load(&p1[lane + 192]);
        }
        float s0 = A0.x*wa.x + A0.y*wa.y + A0.z*wa.z + A0.w*wa.w
                 + B0.x*wb.x + B0.y*wb.y + B0.z*wb.z + B0.w*wb.w;
        float s1 = A1.x*wa.x + A1.y*wa.y + A1.z*wa.z + A1.w*wa.w
                 + B1.x*wb.x + B1.y*wb.y + B1.z*wb.z + B1.w*wb.w;
        s0 = reduce_sum64_dpp(s0);       // VALU-only; no LDS-pipe traffic
        s1 = reduce_sum64_dpp(s1);
        if (lane == 63) {
            float2 gv; gv.x = s0 + bias; gv.y = s1 + bias;
            *(float2*)(g_ws + r) = gv;   // r even -> 8B aligned
        }
        if (!more) break;
        A0 = C0; B0 = D0; A1 = C1; B1 = D1;
        r = rn;
    }
}

// ---------------- Kernel B: per-row prep — transcendentals on all lanes ----------------
__global__ __launch_bounds__(256) void prep_kernel(
    const float* __restrict__ em, const float* __restrict__ g_ws,
    float* __restrict__ out, float* __restrict__ cs_ws, float* __restrict__ P_ws)
{
    const int row  = blockIdx.x * 4 + (threadIdx.x >> 6);   // t*64 + n
    const int t    = row >> 6;
    const int lane = threadIdx.x & 63;
    const size_t base = (size_t)row * TS;

    out[OUT0 + base + lane] = em[base + lane];              // emissions passthrough

    if (t < TT - 1) {
        float g  = g_ws[base + lane];
        float ls = (g >= 0.f) ? -log1pf(__expf(-g)) : (g - log1pf(__expf(g)));
        float c1v = ls - g;
        float2 ctl; ctl.x = ls; ctl.y = c1v;
        ((float2*)(out + OUT2))[base + lane] = ctl;         // controls[t,n,s,:]
        float c1m = (lane == TS - 1) ? 0.f : c1v;
        float cs = scan_sum64(ls) - ls;                     // exclusive prefix sum
        cs_ws[base + lane] = cs;
        P_ws[base + lane]  = c1m + cs;
    }
}

// ---------------- Kernel C: forward/backward recursions per n ----------------
__global__ __launch_bounds__(128) void fb_kernel(
    const float* __restrict__ em, const float* __restrict__ cs_ws,
    const float* __restrict__ P_ws, float* __restrict__ alpha,
    float* __restrict__ beta, float* __restrict__ prior)
{
    const int n    = blockIdx.x;
    const int lane = threadIdx.x & 63;
    const int wv   = threadIdx.x >> 6;

    if (wv == 0) {
        // ---- forward: alpha[t+1] = P + prefixLSE(alpha[t]-cs) + e[t+1] ----
        float a = (lane == 0) ? em[(size_t)n * TS] : NEG;
        alpha[(size_t)n * TS + lane] = a;
        size_t base = (size_t)n * TS;
        float cs = cs_ws[base + lane];
        float P  = P_ws[base + lane];
        float e1 = em[base + NTS + lane];
        for (int t = 0; t < TT - 1; ++t) {
            size_t nbase = base + NTS;
            float csn = cs, Pn = P, e1n = e1;
            if (t < TT - 2) {                       // prefetch next step
                csn = cs_ws[nbase + lane];
                Pn  = P_ws[nbase + lane];
                e1n = em[nbase + NTS + lane];
            }
            a = P + scan_lse64(a - cs) + e1;
            alpha[nbase + lane] = a;
            base = nbase; cs = csn; P = Pn; e1 = e1n;
        }
        float p = a;
        #pragma unroll
        for (int off = 32; off; off >>= 1) p = lse2(p, __shfl_xor(p, off));
        if (lane == 0) prior[n] = p;
    } else {
        // ---- backward, lane-reversed so suffix-LSE becomes prefix-LSE ----
        const int rl = 63 - lane;                   // this lane's state index
        float b = 0.f;
        beta[(size_t)(TT - 1) * NTS + (size_t)n * TS + rl] = 0.f;
        size_t base = (size_t)(TT - 2) * NTS + (size_t)n * TS;
        float cs = cs_ws[base + rl];
        float P  = P_ws[base + rl];
        float e1 = em[base + NTS + rl];
        for (int t = TT - 2; t >= 0; --t) {
            float csn = cs, Pn = P, e1n = e1;
            if (t > 0) {                            // prefetch next step
                csn = cs_ws[base - NTS + rl];
                Pn  = P_ws[base - NTS + rl];
                e1n = em[base + rl];                // em[(t-1)+1] = em[t]
            }
            b = scan_lse64(P + b + e1) - cs;        // prefix over lanes = suffix over states
            beta[base + rl] = b;
            base -= NTS; cs = csn; P = Pn; e1 = e1n;
        }
    }
}

// ---------------- Kernel D: gamma / write / read per (t,n), DPP scans ----------------
__global__ __launch_bounds__(256) void post_kernel(
    const float* __restrict__ em, const float* __restrict__ cs_ws,
    const float* __restrict__ P_ws, const float* __restrict__ alpha,
    const float* __restrict__ beta, const float* __restrict__ prior,
    float* __restrict__ out)
{
    const int row  = blockIdx.x * 4 + (threadIdx.x >> 6);   // t*64 + n
    const int t    = row >> 6;
    const int n    = row & 63;
    const int lane = threadIdx.x & 63;
    const size_t base = (size_t)row * TS;

    float pr = prior[n];
    float a  = alpha[base + lane];
    float bt = beta[base + lane];
    float gm = __expf(a + bt - pr);
    out[OUT1 + base + lane] = gm;
    if (t >= 1) out[OUT4 + base - NTS + lane] = gm;         // write[t-1] = gamma[t]

    if (t < TT - 1) {
        float cs = cs_ws[base + lane];
        float P  = P_ws[base + lane];
        float bn = beta[base + NTS + lane];
        float e1 = em[base + NTS + lane];
        float pu = a - cs;
        float pv = bn + e1 + P - pr;
        float LU = scan_lse64(pu);                  // prefix LSE (i <= k)
        float rv  = __shfl(pv, 63 - lane);          // suffix LSE via lane reversal
        float LVr = scan_lse64(rv);
        float LV  = __shfl(LVr, 63 - lane);
        float LVe = __shfl_down(LV, 1);             // exclusive (j > k)
        if (lane == 63) LVe = NEG;
        out[OUT3 + base + lane] = __expf(LU + LVe);
    }
}

extern "C" void kernel_launch(void* const* d_in, const int* in_sizes, int n_in,
                              void* d_out, int out_size, void* d_ws, size_t ws_size,
                              hipStream_t stream) {
    const float* x  = (const float*)d_in[0];
    const float* em = (const float*)d_in[1];
    const float* w  = (const float*)d_in[2];
    const float* bb = (const float*)d_in[3];
    float* out = (float*)d_out;

    char* ws = (char*)d_ws;
    float* g_ws   = (float*)(ws);                    // 1 MB
    float* cs_ws  = (float*)(ws + (1u << 20));       // 1 MB
    float* P_ws   = (float*)(ws + (2u << 20));       // 1 MB
    float* alpha  = (float*)(ws + (3u << 20));       // 1 MB
    float* beta   = (float*)(ws + (4u << 20));       // 1 MB
    float* prior  = (float*)(ws + (5u << 20));       // 256 B

    gate_kernel<<<2048, 256, 0, stream>>>(x, w, bb, g_ws);
    prep_kernel<<<TT * NN / 4, 256, 0, stream>>>(em, g_ws, out, cs_ws, P_ws);
    fb_kernel<<<NN, 128, 0, stream>>>(em, cs_ws, P_ws, alpha, beta, prior);
    post_kernel<<<TT * NN / 4, 256, 0, stream>>>(em, cs_ws, P_ws, alpha, beta, prior, out);
}